// Round 1
// baseline (175.773 us; speedup 1.0000x reference)
//
#include <hip/hip_runtime.h>

#define NG 128      // graphs
#define NPG 64      // nodes per graph
#define IN 16
#define DM 128      // d_model
#define NOUT 64
#define EPG 4096    // edges per graph (64x64)
#define KC 32       // K-chunk of big GEMM
#define NCHUNK 164  // 5248/32
#define BN_EPS 1e-5f

// ---------------------------------------------------------------------------
// K1: per-graph fused conv1 + pooled.
//   dinv[j] = rsqrt(col-sum of ew);  t[i] = dinv[i]*(Σ_j ew[i,j]dinv[j])/64
//   P = x@W1 (64x16 @ 16x128);  h1[j,f] = relu(dinv_j*Σ_i dinv_i ew[i,j] P[i,f] + b1)
//   z[f] = Σ_j t[j]*h1[j,f];  pooled[g,f] = relu(Σ_k z[k] W2[k,f] + b2[f])
// Block 0 also zeroes the 768-float stats region (K4a accumulates atomically).
// ---------------------------------------------------------------------------
__global__ __launch_bounds__(256) void k_conv1(
    const float* __restrict__ x, const float* __restrict__ ew,
    const float* __restrict__ W1, const float* __restrict__ b1,
    const float* __restrict__ W2, const float* __restrict__ b2,
    float* __restrict__ pooled, float* __restrict__ stats)
{
    __shared__ float ew_s[EPG];        // [i][j] 16KB (later scaled to dinv_i*ew)
    __shared__ float x_s[NPG * IN];    // 4KB
    __shared__ float W1_s[IN * DM];    // 8KB
    __shared__ float P_s[NPG * DM];    // 32KB
    __shared__ float b1_s[DM];
    __shared__ float dinv_s[NPG];
    __shared__ float t_s[NPG];
    __shared__ float z_s[DM];

    const int g = blockIdx.x, t = threadIdx.x;
    if (g == 0) {   // zero stats scratch (stats0 needs it; rest harmless)
        for (int i = t; i < 768; i += 256) stats[i] = 0.f;
    }
    const float* ewg = ew + g * EPG;
    for (int i = t; i < EPG; i += 256)      ew_s[i] = ewg[i];
    for (int i = t; i < NPG * IN; i += 256) x_s[i]  = x[g * NPG * IN + i];
    for (int i = t; i < IN * DM; i += 256)  W1_s[i] = W1[i];
    if (t < DM) b1_s[t] = b1[t];
    __syncthreads();

    // deg / dinv: column sums (lanes read consecutive -> conflict-free)
    if (t < NPG) {
        float s = 0.f;
        #pragma unroll 8
        for (int i = 0; i < NPG; i++) s += ew_s[i * NPG + t];
        dinv_s[t] = (s > 0.f) ? rsqrtf(s) : 0.f;
    }
    __syncthreads();

    // t_s via per-wave row reduction (lane j reads row i at col j: conflict-free)
    {
        const int j = t & 63, q = t >> 6;
        const float dj = dinv_s[j];
        for (int i = q * 16; i < q * 16 + 16; i++) {
            float vv = ew_s[i * NPG + j] * dj;
            #pragma unroll
            for (int off = 32; off > 0; off >>= 1) vv += __shfl_down(vv, off, 64);
            if (j == 0) t_s[i] = dinv_s[i] * vv * (1.f / 64.f);
        }
    }

    // P = x @ W1 : thread (ih = t>>7, f = t&127) does 32 rows
    {
        const int f = t & 127, ih = t >> 7;
        for (int i = ih * 32; i < ih * 32 + 32; i++) {
            float acc = 0.f;
            #pragma unroll
            for (int k = 0; k < IN; k++) acc += x_s[i * IN + k] * W1_s[k * DM + f];
            P_s[i * DM + f] = acc;
        }
    }
    __syncthreads();

    // scale rows in place: ew_s[i][j] = dinv_i * ew[i][j]
    for (int i = t; i < EPG; i += 256) ew_s[i] *= dinv_s[i >> 6];
    __syncthreads();

    // aggregation + relu + z: thread (j = t&63, q = t>>6) owns h1[j, q*32 .. +31]
    {
        const int j = t & 63, q = t >> 6, fb = q * 32;
        float acc[32];
        #pragma unroll
        for (int u = 0; u < 32; u++) acc[u] = 0.f;
        for (int i = 0; i < NPG; i++) {
            const float w = ew_s[i * NPG + j];                    // 2-way (free)
            const float4* p4 = (const float4*)(P_s + i * DM + fb); // broadcast
            #pragma unroll
            for (int u4 = 0; u4 < 8; u4++) {
                float4 p = p4[u4];
                acc[4 * u4 + 0] += w * p.x;
                acc[4 * u4 + 1] += w * p.y;
                acc[4 * u4 + 2] += w * p.z;
                acc[4 * u4 + 3] += w * p.w;
            }
        }
        const float dj = dinv_s[j], tj = t_s[j];
        #pragma unroll
        for (int u = 0; u < 32; u++) {
            float h = fmaxf(dj * acc[u] + b1_s[fb + u], 0.f);
            float zv = tj * h;                  // wave q = lanes j 0..63
            #pragma unroll
            for (int off = 32; off > 0; off >>= 1) zv += __shfl_down(zv, off, 64);
            if (j == 0) z_s[fb + u] = zv;
        }
    }
    __syncthreads();

    // pooled[g,f] = relu(z @ W2 + b2)   (W2 column-coalesced across lanes, L2-hot)
    if (t < DM) {
        float acc = b2[t];
        #pragma unroll 8
        for (int k = 0; k < DM; k++) acc += z_s[k] * W2[k * DM + t];
        pooled[g * DM + t] = fmaxf(acc, 0.f);
    }
}

// ---------------------------------------------------------------------------
// K3: big GEMM partials. feat[128 x 5248] @ Wm0[5248 x 128], split-K.
// Block c handles feat columns [c*32, c*32+32) addressed straight from the
// source (pooled / relu(x) / ew) -- feat never materialized.
// Full 128x128 output tile, 16x16 threads, 8x8 register blocking.
// ---------------------------------------------------------------------------
__global__ __launch_bounds__(256) void k_gemm_part(
    const float* __restrict__ pooled, const float* __restrict__ x,
    const float* __restrict__ ew, const float* __restrict__ Wm0,
    float* __restrict__ part)
{
    __shared__ float a_s[KC * 132];   // [k][g], pad 132 keeps 16B align + banks
    __shared__ float b_s[KC * DM];    // [k][f]
    const int c = blockIdx.x, t = threadIdx.x;

    const float* src; int stride, off;
    if (c < 4)       { src = pooled; stride = 128;  off = c * 32; }
    else if (c < 36) { src = x;      stride = 1024; off = c * 32 - 128; }
    else             { src = ew;     stride = 4096; off = c * 32 - 1152; }

    for (int idx = t; idx < 128 * KC; idx += 256) {
        int gg = idx >> 5, k = idx & 31;
        a_s[k * 132 + gg] = fmaxf(src[gg * stride + off + k], 0.f);  // feat relu
    }
    for (int idx = t; idx < KC * DM; idx += 256)
        b_s[idx] = Wm0[c * (KC * DM) + idx];   // rows kg0..kg0+31 contiguous
    __syncthreads();

    const int tf = t & 15, tg = t >> 4;
    const int g0 = tg * 8, f0 = tf * 8;
    float acc[8][8];
    #pragma unroll
    for (int i = 0; i < 8; i++)
        #pragma unroll
        for (int jx = 0; jx < 8; jx++) acc[i][jx] = 0.f;

    #pragma unroll 4
    for (int k = 0; k < KC; k++) {
        const float4 a0 = *(const float4*)(a_s + k * 132 + g0);
        const float4 a1 = *(const float4*)(a_s + k * 132 + g0 + 4);
        const float4 c0 = *(const float4*)(b_s + k * DM + f0);
        const float4 c1 = *(const float4*)(b_s + k * DM + f0 + 4);
        const float av[8] = {a0.x, a0.y, a0.z, a0.w, a1.x, a1.y, a1.z, a1.w};
        const float bv[8] = {c0.x, c0.y, c0.z, c0.w, c1.x, c1.y, c1.z, c1.w};
        #pragma unroll
        for (int i = 0; i < 8; i++)
            #pragma unroll
            for (int jx = 0; jx < 8; jx++) acc[i][jx] += av[i] * bv[jx];
    }

    float* pp = part + c * 16384;
    #pragma unroll
    for (int i = 0; i < 8; i++) {
        float4* o = (float4*)(pp + (g0 + i) * 128 + f0);
        o[0] = make_float4(acc[i][0], acc[i][1], acc[i][2], acc[i][3]);
        o[1] = make_float4(acc[i][4], acc[i][5], acc[i][6], acc[i][7]);
    }
}

// ---------------------------------------------------------------------------
// K4a: reduce 164 partials + bm0 + relu -> v0; atomic per-column BN0 stats.
// 256 blocks = 32 g-tiles x 8 f-groups; 256 thr = 4 c-quarters x 4 g x 16 f.
// ---------------------------------------------------------------------------
__global__ __launch_bounds__(256) void k_reduce_bn0(
    const float* __restrict__ part, const float* __restrict__ bm0,
    float* __restrict__ v0, float* __restrict__ stats0)
{
    const int bx = blockIdx.x, t = threadIdx.x;
    const int fgrp = bx & 7, gt = bx >> 3;
    const int fsub = t & 15, gl = (t >> 4) & 3, ch = t >> 6;
    const int f = fgrp * 16 + fsub, g = gt * 4 + gl;

    const float* p = part + g * 128 + f + (size_t)ch * 41 * 16384;
    float v = 0.f;
    #pragma unroll 8
    for (int cc = 0; cc < 41; cc++) v += p[cc * 16384];

    __shared__ float r1[256];
    r1[t] = v;
    __syncthreads();
    __shared__ float sv[64], sv2[64];
    if (ch == 0) {
        v = r1[t] + r1[t + 64] + r1[t + 128] + r1[t + 192] + bm0[f];
        v = fmaxf(v, 0.f);
        v0[g * 128 + f] = v;
        sv[t] = v; sv2[t] = v * v;
    }
    __syncthreads();
    if (t < 16) {
        float s1 = sv[t] + sv[t + 16] + sv[t + 32] + sv[t + 48];
        float s2 = sv2[t] + sv2[t + 16] + sv2[t + 32] + sv2[t + 48];
        atomicAdd(&stats0[(fgrp * 16 + t) * 2], s1);
        atomicAdd(&stats0[(fgrp * 16 + t) * 2 + 1], s2);
    }
}

// ---------------------------------------------------------------------------
// K5/K6: one MLP layer. Block = output column f (owns the whole column ->
// in-block BN stats, no atomics). BN of the PREVIOUS layer folded into load.
// ---------------------------------------------------------------------------
__global__ __launch_bounds__(128) void k_mlp(
    const float* __restrict__ vin, const float* __restrict__ statsin,
    const float* __restrict__ gbn, const float* __restrict__ bbn,
    const float* __restrict__ W, const float* __restrict__ bias,
    float* __restrict__ vout, float* __restrict__ statsout)
{
    __shared__ float h_s[128 * 129];
    __shared__ float wcol[128];
    __shared__ float scale_s[128], shift_s[128];
    __shared__ float rr[4];
    const int f = blockIdx.x, t = threadIdx.x;
    {
        float s1 = statsin[t * 2], s2 = statsin[t * 2 + 1];
        float m = s1 * (1.f / 128.f);
        float var = s2 * (1.f / 128.f) - m * m;
        float sc = gbn[t] * rsqrtf(var + BN_EPS);
        scale_s[t] = sc;
        shift_s[t] = bbn[t] - m * sc;
        wcol[t] = W[t * 128 + f];
    }
    __syncthreads();
    for (int it = 0; it < 128; it++)
        h_s[it * 129 + t] = vin[it * 128 + t] * scale_s[t] + shift_s[t];
    __syncthreads();
    float acc = bias[f];
    #pragma unroll 8
    for (int k = 0; k < 128; k++) acc += h_s[t * 129 + k] * wcol[k];
    acc = fmaxf(acc, 0.f);
    vout[t * 128 + f] = acc;
    float s1 = acc, s2 = acc * acc;
    #pragma unroll
    for (int off = 32; off > 0; off >>= 1) {
        s1 += __shfl_down(s1, off, 64);
        s2 += __shfl_down(s2, off, 64);
    }
    if ((t & 63) == 0) { rr[(t >> 6) * 2] = s1; rr[(t >> 6) * 2 + 1] = s2; }
    __syncthreads();
    if (t == 0) {
        statsout[f * 2]     = rr[0] + rr[2];
        statsout[f * 2 + 1] = rr[1] + rr[3];
    }
}

// ---------------------------------------------------------------------------
// K7: output layer (BN2 folded at load). Block = output column o (64 blocks).
// ---------------------------------------------------------------------------
__global__ __launch_bounds__(128) void k_out(
    const float* __restrict__ vin, const float* __restrict__ statsin,
    const float* __restrict__ gbn, const float* __restrict__ bbn,
    const float* __restrict__ Wo, const float* __restrict__ bo,
    float* __restrict__ out)
{
    __shared__ float h_s[128 * 129];
    __shared__ float wcol[128];
    __shared__ float scale_s[128], shift_s[128];
    const int o = blockIdx.x, t = threadIdx.x;
    {
        float s1 = statsin[t * 2], s2 = statsin[t * 2 + 1];
        float m = s1 * (1.f / 128.f);
        float var = s2 * (1.f / 128.f) - m * m;
        float sc = gbn[t] * rsqrtf(var + BN_EPS);
        scale_s[t] = sc;
        shift_s[t] = bbn[t] - m * sc;
        wcol[t] = Wo[t * NOUT + o];
    }
    __syncthreads();
    for (int it = 0; it < 128; it++)
        h_s[it * 129 + t] = vin[it * 128 + t] * scale_s[t] + shift_s[t];
    __syncthreads();
    float acc = bo[o];
    #pragma unroll 8
    for (int k = 0; k < 128; k++) acc += h_s[t * 129 + k] * wcol[k];
    out[t * NOUT + o] = acc;
}

extern "C" void kernel_launch(void* const* d_in, const int* in_sizes, int n_in,
                              void* d_out, int out_size, void* d_ws, size_t ws_size,
                              hipStream_t stream)
{
    const float* x   = (const float*)d_in[0];
    // d_in[1] = edge_index (structure known: complete graphs), d_in[3] = batch
    const float* ew  = (const float*)d_in[2];
    const float* W1  = (const float*)d_in[4];
    const float* b1  = (const float*)d_in[5];
    const float* W2  = (const float*)d_in[6];
    const float* b2  = (const float*)d_in[7];
    const float* Wm0 = (const float*)d_in[8];
    const float* bm0 = (const float*)d_in[9];
    const float* g0  = (const float*)d_in[10];
    const float* be0 = (const float*)d_in[11];
    const float* Wm1 = (const float*)d_in[12];
    const float* bm1 = (const float*)d_in[13];
    const float* g1  = (const float*)d_in[14];
    const float* be1 = (const float*)d_in[15];
    const float* Wm2 = (const float*)d_in[16];
    const float* bm2 = (const float*)d_in[17];
    const float* g2  = (const float*)d_in[18];
    const float* be2 = (const float*)d_in[19];
    const float* Wo  = (const float*)d_in[20];
    const float* bo  = (const float*)d_in[21];

    float* ws     = (float*)d_ws;
    float* pooled = ws;                       // 16384
    float* part   = pooled + 16384;           // 164*16384
    float* v0     = part + NCHUNK * 16384;    // 16384
    float* v1     = v0 + 16384;               // 16384
    float* v2     = v1 + 16384;               // 16384
    float* stats  = v2 + 16384;               // 768 (stats0|stats1|stats2)

    k_conv1<<<NG, 256, 0, stream>>>(x, ew, W1, b1, W2, b2, pooled, stats);
    k_gemm_part<<<NCHUNK, 256, 0, stream>>>(pooled, x, ew, Wm0, part);
    k_reduce_bn0<<<256, 256, 0, stream>>>(part, bm0, v0, stats);
    k_mlp<<<128, 128, 0, stream>>>(v0, stats,       g0, be0, Wm1, bm1, v1, stats + 256);
    k_mlp<<<128, 128, 0, stream>>>(v1, stats + 256, g1, be1, Wm2, bm2, v2, stats + 512);
    k_out<<<NOUT, 128, 0, stream>>>(v2, stats + 512, g2, be2, Wo, bo, (float*)d_out);
}

// Round 2
// 160.186 us; speedup vs baseline: 1.0973x; 1.0973x over previous
//
#include <hip/hip_runtime.h>

#define NG 128      // graphs
#define NPG 64      // nodes per graph
#define IN 16
#define DM 128      // d_model
#define NOUT 64
#define EPG 4096    // edges per graph (64x64)
#define KC 32       // K-chunk of big GEMM
#define NCHUNK 164  // 5248/32
#define BN_EPS 1e-5f

// ---------------------------------------------------------------------------
// K1: per-(graph, f-half) fused conv1 + z-half.  Grid 256 = g*2 + half.
//   dinv[j] = rsqrt(col-sum of ew);  t[i] = dinv[i]*(Σ_j ew[i,j]dinv[j])/64
//   P = x@W1h (64x16 @ 16x64);  h1[j,f] = relu(dinv_j*Σ_i dinv_i ew[i,j] P[i,f] + b1)
//   z[g, half*64+f] = Σ_j t[j]*h1[j,f]        (pooled computed in k_gemm_part)
// Block 0 also zeroes the 768-float stats region (K4a accumulates atomically).
// ---------------------------------------------------------------------------
__global__ __launch_bounds__(256) void k_conv1(
    const float* __restrict__ x, const float* __restrict__ ew,
    const float* __restrict__ W1, const float* __restrict__ b1,
    float* __restrict__ z, float* __restrict__ stats)
{
    __shared__ float ew_s[EPG];         // 16KB [i][j], later scaled by dinv_i
    __shared__ float x_s[NPG * IN];     // 4KB
    __shared__ float W1h_s[IN * 64];    // 4KB (this block's f-half)
    __shared__ float P_s[NPG * 64];     // 16KB
    __shared__ float b1h_s[64];
    __shared__ float dinv_s[NPG];
    __shared__ float t_s[NPG];

    const int g = blockIdx.x >> 1, half = blockIdx.x & 1, t = threadIdx.x;
    const int fh0 = half * 64;
    if (blockIdx.x == 0) {
        for (int i = t; i < 768; i += 256) stats[i] = 0.f;
    }
    // stage (vectorized)
    {
        const float4* ew4 = (const float4*)(ew + g * EPG);
        float4* ews4 = (float4*)ew_s;
        #pragma unroll
        for (int i = 0; i < 4; i++) ews4[t + 256 * i] = ew4[t + 256 * i];
        ((float4*)x_s)[t] = ((const float4*)(x + g * NPG * IN))[t];
    }
    for (int i = t; i < IN * 64; i += 256)
        W1h_s[i] = W1[(i >> 6) * DM + fh0 + (i & 63)];
    if (t < 64) b1h_s[t] = b1[fh0 + t];
    __syncthreads();

    // dinv: column sums (lanes consecutive -> conflict-free)
    if (t < NPG) {
        float s = 0.f;
        #pragma unroll 8
        for (int i = 0; i < NPG; i++) s += ew_s[i * NPG + t];
        dinv_s[t] = (s > 0.f) ? rsqrtf(s) : 0.f;
    }
    __syncthreads();

    // t_s: per-wave row reductions
    {
        const int j = t & 63, q = t >> 6;
        const float dj = dinv_s[j];
        for (int i = q * 16; i < q * 16 + 16; i++) {
            float vv = ew_s[i * NPG + j] * dj;
            #pragma unroll
            for (int off = 32; off > 0; off >>= 1) vv += __shfl_down(vv, off, 64);
            if (j == 0) t_s[i] = dinv_s[i] * vv * (1.f / 64.f);
        }
    }

    // P = x @ W1h : thread (f = t&63, ih = t>>6) does 16 rows
    {
        const int f = t & 63, ih = t >> 6;
        for (int i = ih * 16; i < ih * 16 + 16; i++) {
            float acc = 0.f;
            #pragma unroll
            for (int k = 0; k < IN; k++) acc += x_s[i * IN + k] * W1h_s[k * 64 + f];
            P_s[i * 64 + f] = acc;
        }
    }
    __syncthreads();

    // scale rows in place: ew_s[i][j] = dinv_i * ew[i][j]
    for (int i = t; i < EPG; i += 256) ew_s[i] *= dinv_s[i >> 6];
    __syncthreads();

    // aggregation + relu + z-half: thread (j = t&63, q = t>>6) owns 16 f's
    {
        const int j = t & 63, q = t >> 6, fb = q * 16;
        float acc[16];
        #pragma unroll
        for (int u = 0; u < 16; u++) acc[u] = 0.f;
        for (int i = 0; i < NPG; i++) {
            const float w = ew_s[i * NPG + j];                    // 2-way (free)
            const float4* p4 = (const float4*)(P_s + i * 64 + fb); // wave-uniform
            #pragma unroll
            for (int u4 = 0; u4 < 4; u4++) {
                float4 p = p4[u4];
                acc[4 * u4 + 0] += w * p.x;
                acc[4 * u4 + 1] += w * p.y;
                acc[4 * u4 + 2] += w * p.z;
                acc[4 * u4 + 3] += w * p.w;
            }
        }
        const float dj = dinv_s[j], tj = t_s[j];
        #pragma unroll
        for (int u = 0; u < 16; u++) {
            float h = fmaxf(dj * acc[u] + b1h_s[fb + u], 0.f);
            float zv = tj * h;
            #pragma unroll
            for (int off = 32; off > 0; off >>= 1) zv += __shfl_down(zv, off, 64);
            if (j == 0) z[g * DM + fh0 + fb + u] = zv;
        }
    }
}

// ---------------------------------------------------------------------------
// K3: big GEMM partials. feat[128 x 5248] @ Wm0[5248 x 128], split-K.
// Block c handles feat cols [c*32, c*32+32). c<4: compute pooled slice from z
// (pooled = relu(z@W2 + b2)) directly into a_s; else load from x / ew.
// ---------------------------------------------------------------------------
__global__ __launch_bounds__(256) void k_gemm_part(
    const float* __restrict__ z, const float* __restrict__ x,
    const float* __restrict__ ew, const float* __restrict__ W2,
    const float* __restrict__ b2, const float* __restrict__ Wm0,
    float* __restrict__ part)
{
    __shared__ float a_s[KC * 132];    // [k][g]
    __shared__ float b_s[KC * DM];     // [k][f]
    __shared__ float z_s[DM * 129];    // 64.5KB (c<4 only)
    __shared__ float W2_s[DM * 32];    // 16KB   (c<4 only)
    const int c = blockIdx.x, t = threadIdx.x;

    if (c < 4) {
        // stage z (pad 129 -> conflict-free reads) and the 32-col W2 slice
        for (int it = 0; it < 64; it++) {
            int idx = it * 256 + t;
            z_s[(idx >> 7) * 129 + (idx & 127)] = z[idx];
        }
        for (int idx = t; idx < DM * 32; idx += 256)
            W2_s[idx] = W2[(idx >> 5) * DM + c * 32 + (idx & 31)];
        __syncthreads();
        // pooled slice: thread (g = t>>1, kh = t&1) computes 16 k's
        const int gg = t >> 1, kh = t & 1, k0 = kh * 16;
        float acc[16];
        #pragma unroll
        for (int u = 0; u < 16; u++) acc[u] = 0.f;
        for (int kk = 0; kk < DM; kk++) {
            const float zv = z_s[gg * 129 + kk];               // 2-way (free)
            const float4* w4 = (const float4*)(W2_s + kk * 32 + k0); // near-uniform
            #pragma unroll
            for (int u4 = 0; u4 < 4; u4++) {
                float4 w = w4[u4];
                acc[4 * u4 + 0] += zv * w.x;
                acc[4 * u4 + 1] += zv * w.y;
                acc[4 * u4 + 2] += zv * w.z;
                acc[4 * u4 + 3] += zv * w.w;
            }
        }
        #pragma unroll
        for (int u = 0; u < 16; u++)
            a_s[(k0 + u) * 132 + gg] = fmaxf(acc[u] + b2[c * 32 + k0 + u], 0.f);
    } else {
        const float* src; int stride, off;
        if (c < 36) { src = x;  stride = 1024; off = c * 32 - 128; }
        else        { src = ew; stride = 4096; off = c * 32 - 1152; }
        for (int idx = t; idx < 128 * KC; idx += 256) {
            int gg = idx >> 5, k = idx & 31;
            a_s[k * 132 + gg] = fmaxf(src[gg * stride + off + k], 0.f);
        }
    }
    for (int idx = t; idx < KC * DM; idx += 256)
        b_s[idx] = Wm0[c * (KC * DM) + idx];
    __syncthreads();

    const int tf = t & 15, tg = t >> 4;
    const int g0 = tg * 8, f0 = tf * 8;
    float acc[8][8];
    #pragma unroll
    for (int i = 0; i < 8; i++)
        #pragma unroll
        for (int jx = 0; jx < 8; jx++) acc[i][jx] = 0.f;

    #pragma unroll 4
    for (int k = 0; k < KC; k++) {
        const float4 a0 = *(const float4*)(a_s + k * 132 + g0);
        const float4 a1 = *(const float4*)(a_s + k * 132 + g0 + 4);
        const float4 c0 = *(const float4*)(b_s + k * DM + f0);
        const float4 c1 = *(const float4*)(b_s + k * DM + f0 + 4);
        const float av[8] = {a0.x, a0.y, a0.z, a0.w, a1.x, a1.y, a1.z, a1.w};
        const float bv[8] = {c0.x, c0.y, c0.z, c0.w, c1.x, c1.y, c1.z, c1.w};
        #pragma unroll
        for (int i = 0; i < 8; i++)
            #pragma unroll
            for (int jx = 0; jx < 8; jx++) acc[i][jx] += av[i] * bv[jx];
    }

    float* pp = part + c * 16384;
    #pragma unroll
    for (int i = 0; i < 8; i++) {
        float4* o = (float4*)(pp + (g0 + i) * 128 + f0);
        o[0] = make_float4(acc[i][0], acc[i][1], acc[i][2], acc[i][3]);
        o[1] = make_float4(acc[i][4], acc[i][5], acc[i][6], acc[i][7]);
    }
}

// ---------------------------------------------------------------------------
// K4a: reduce 164 partials + bm0 + relu -> v0; atomic per-column BN0 stats.
// ---------------------------------------------------------------------------
__global__ __launch_bounds__(256) void k_reduce_bn0(
    const float* __restrict__ part, const float* __restrict__ bm0,
    float* __restrict__ v0, float* __restrict__ stats0)
{
    const int bx = blockIdx.x, t = threadIdx.x;
    const int fgrp = bx & 7, gt = bx >> 3;
    const int fsub = t & 15, gl = (t >> 4) & 3, ch = t >> 6;
    const int f = fgrp * 16 + fsub, g = gt * 4 + gl;

    const float* p = part + g * 128 + f + (size_t)ch * 41 * 16384;
    float v = 0.f;
    #pragma unroll 8
    for (int cc = 0; cc < 41; cc++) v += p[cc * 16384];

    __shared__ float r1[256];
    r1[t] = v;
    __syncthreads();
    __shared__ float sv[64], sv2[64];
    if (ch == 0) {
        v = r1[t] + r1[t + 64] + r1[t + 128] + r1[t + 192] + bm0[f];
        v = fmaxf(v, 0.f);
        v0[g * 128 + f] = v;
        sv[t] = v; sv2[t] = v * v;
    }
    __syncthreads();
    if (t < 16) {
        float s1 = sv[t] + sv[t + 16] + sv[t + 32] + sv[t + 48];
        float s2 = sv2[t] + sv2[t + 16] + sv2[t + 32] + sv2[t + 48];
        atomicAdd(&stats0[(fgrp * 16 + t) * 2], s1);
        atomicAdd(&stats0[(fgrp * 16 + t) * 2 + 1], s2);
    }
}

// ---------------------------------------------------------------------------
// K5/K6: one MLP layer. Block = output column f; 256 threads (split-K dot).
// BN of the PREVIOUS layer folded into the staging load.
// ---------------------------------------------------------------------------
__global__ __launch_bounds__(256) void k_mlp(
    const float* __restrict__ vin, const float* __restrict__ statsin,
    const float* __restrict__ gbn, const float* __restrict__ bbn,
    const float* __restrict__ W, const float* __restrict__ bias,
    float* __restrict__ vout, float* __restrict__ statsout)
{
    __shared__ float h_s[128 * 129];
    __shared__ float wcol[128];
    __shared__ float scale_s[128], shift_s[128];
    __shared__ float pc[128];
    __shared__ float rr[4];
    const int f = blockIdx.x, t = threadIdx.x;
    if (t < 128) {
        float s1 = statsin[t * 2], s2 = statsin[t * 2 + 1];
        float m = s1 * (1.f / 128.f);
        float var = s2 * (1.f / 128.f) - m * m;
        float sc = gbn[t] * rsqrtf(var + BN_EPS);
        scale_s[t] = sc;
        shift_s[t] = bbn[t] - m * sc;
        wcol[t] = W[t * 128 + f];
    }
    __syncthreads();
    #pragma unroll 4
    for (int it = 0; it < 64; it++) {
        int idx = it * 256 + t;
        int g = idx >> 7, k = idx & 127;
        h_s[g * 129 + k] = vin[idx] * scale_s[k] + shift_s[k];
    }
    __syncthreads();
    const int g = t & 127, kh = t >> 7;
    float acc = 0.f;
    #pragma unroll 8
    for (int k = kh * 64; k < kh * 64 + 64; k++) acc += h_s[g * 129 + k] * wcol[k];
    if (kh) pc[g] = acc;
    __syncthreads();
    if (t < 128) {
        float v = fmaxf(acc + pc[t] + bias[f], 0.f);
        vout[t * 128 + f] = v;
        float s1 = v, s2 = v * v;
        #pragma unroll
        for (int off = 32; off > 0; off >>= 1) {
            s1 += __shfl_down(s1, off, 64);
            s2 += __shfl_down(s2, off, 64);
        }
        if ((t & 63) == 0) { rr[(t >> 6) * 2] = s1; rr[(t >> 6) * 2 + 1] = s2; }
    }
    __syncthreads();
    if (t == 0) {
        statsout[f * 2]     = rr[0] + rr[2];
        statsout[f * 2 + 1] = rr[1] + rr[3];
    }
}

// ---------------------------------------------------------------------------
// K7: output layer (BN2 folded at load). Block = 2 graph rows; coalesced out.
// ---------------------------------------------------------------------------
__global__ __launch_bounds__(128) void k_out(
    const float* __restrict__ vin, const float* __restrict__ statsin,
    const float* __restrict__ gbn, const float* __restrict__ bbn,
    const float* __restrict__ Wo, const float* __restrict__ bo,
    float* __restrict__ out)
{
    __shared__ float Wo_s[128 * 64];   // 32KB
    __shared__ float vrow[2][128];
    __shared__ float scale_s[128], shift_s[128];
    const int b = blockIdx.x, t = threadIdx.x, g0 = b * 2;
    {
        float s1 = statsin[t * 2], s2 = statsin[t * 2 + 1];
        float m = s1 * (1.f / 128.f);
        float var = s2 * (1.f / 128.f) - m * m;
        float sc = gbn[t] * rsqrtf(var + BN_EPS);
        scale_s[t] = sc;
        shift_s[t] = bbn[t] - m * sc;
    }
    __syncthreads();
    #pragma unroll 8
    for (int it = 0; it < 64; it++) {
        int idx = it * 128 + t;
        Wo_s[idx] = Wo[idx];
    }
    #pragma unroll
    for (int it = 0; it < 2; it++) {
        int idx = it * 128 + t;
        int g2 = idx >> 7, k = idx & 127;
        vrow[g2][k] = vin[(g0 + g2) * 128 + k] * scale_s[k] + shift_s[k];
    }
    __syncthreads();
    const int g2 = t >> 6, o = t & 63;
    float acc = bo[o];
    #pragma unroll 8
    for (int k = 0; k < 128; k++) acc += vrow[g2][k] * Wo_s[k * 64 + o];
    out[(g0 + g2) * NOUT + o] = acc;
}

extern "C" void kernel_launch(void* const* d_in, const int* in_sizes, int n_in,
                              void* d_out, int out_size, void* d_ws, size_t ws_size,
                              hipStream_t stream)
{
    const float* x   = (const float*)d_in[0];
    const float* ew  = (const float*)d_in[2];
    const float* W1  = (const float*)d_in[4];
    const float* b1  = (const float*)d_in[5];
    const float* W2  = (const float*)d_in[6];
    const float* b2  = (const float*)d_in[7];
    const float* Wm0 = (const float*)d_in[8];
    const float* bm0 = (const float*)d_in[9];
    const float* g0  = (const float*)d_in[10];
    const float* be0 = (const float*)d_in[11];
    const float* Wm1 = (const float*)d_in[12];
    const float* bm1 = (const float*)d_in[13];
    const float* g1  = (const float*)d_in[14];
    const float* be1 = (const float*)d_in[15];
    const float* Wm2 = (const float*)d_in[16];
    const float* bm2 = (const float*)d_in[17];
    const float* g2  = (const float*)d_in[18];
    const float* be2 = (const float*)d_in[19];
    const float* Wo  = (const float*)d_in[20];
    const float* bo  = (const float*)d_in[21];

    float* ws    = (float*)d_ws;
    float* zbuf  = ws;                        // 16384
    float* part  = zbuf + 16384;              // 164*16384
    float* v0    = part + NCHUNK * 16384;     // 16384
    float* v1    = v0 + 16384;                // 16384
    float* v2    = v1 + 16384;                // 16384
    float* stats = v2 + 16384;                // 768 (stats0|stats1|stats2)

    k_conv1<<<NG * 2, 256, 0, stream>>>(x, ew, W1, b1, zbuf, stats);
    k_gemm_part<<<NCHUNK, 256, 0, stream>>>(zbuf, x, ew, W2, b2, Wm0, part);
    k_reduce_bn0<<<256, 256, 0, stream>>>(part, bm0, v0, stats);
    k_mlp<<<128, 256, 0, stream>>>(v0, stats,       g0, be0, Wm1, bm1, v1, stats + 256);
    k_mlp<<<128, 256, 0, stream>>>(v1, stats + 256, g1, be1, Wm2, bm2, v2, stats + 512);
    k_out<<<NOUT, 128, 0, stream>>>(v2, stats + 512, g2, be2, Wo, bo, (float*)d_out);
}

// Round 3
// 148.239 us; speedup vs baseline: 1.1857x; 1.0806x over previous
//
#include <hip/hip_runtime.h>

#define NG 128      // graphs
#define NPG 64      // nodes per graph
#define IN 16
#define DM 128      // d_model
#define NOUT 64
#define EPG 4096    // edges per graph (64x64)
#define NGEMM 160   // x/ew chunks: 80 k-chunks(64) x 2 f-halves(64)
#define BN_EPS 1e-5f

// ---------------------------------------------------------------------------
// K_A "front": blocks 0..255 = conv1 per (graph, f-half) -> z;
//              blocks 256..415 = big-GEMM x/ew chunks (64k x 64f) -> part.
// No dependency between the two halves; they share one dispatch.
// Block 0 also zeroes the 768-float stats region.
// ---------------------------------------------------------------------------
__global__ __launch_bounds__(256) void k_front(
    const float* __restrict__ x, const float* __restrict__ ew,
    const float* __restrict__ W1, const float* __restrict__ b1,
    const float* __restrict__ Wm0,
    float* __restrict__ z, float* __restrict__ part, float* __restrict__ stats)
{
    __shared__ float u[12544];   // 49KB union: conv needs 10432, gemm 12544
    const int b = blockIdx.x, t = threadIdx.x;

    if (b < 256) {
        // ---------------- conv path ----------------
        float* ew_s   = u;            // 4096  [i][j], later scaled by dinv_i
        float* x_s    = u + 4096;     // 1024
        float* W1h_s  = u + 5120;     // 1024
        float* P_s    = u + 6144;     // 4096
        float* b1h_s  = u + 10240;    // 64
        float* dinv_s = u + 10304;    // 64
        float* t_s    = u + 10368;    // 64
        const int g = b >> 1, half = b & 1, fh0 = half * 64;
        if (b == 0) {
            for (int i = t; i < 768; i += 256) stats[i] = 0.f;
        }
        {
            const float4* ew4 = (const float4*)(ew + g * EPG);
            float4* ews4 = (float4*)ew_s;
            #pragma unroll
            for (int i = 0; i < 4; i++) ews4[t + 256 * i] = ew4[t + 256 * i];
            ((float4*)x_s)[t] = ((const float4*)(x + g * NPG * IN))[t];
        }
        for (int i = t; i < IN * 64; i += 256)
            W1h_s[i] = W1[(i >> 6) * DM + fh0 + (i & 63)];
        if (t < 64) b1h_s[t] = b1[fh0 + t];
        __syncthreads();

        // dinv: column sums (lanes consecutive -> conflict-free)
        if (t < NPG) {
            float s = 0.f;
            #pragma unroll 8
            for (int i = 0; i < NPG; i++) s += ew_s[i * NPG + t];
            dinv_s[t] = (s > 0.f) ? rsqrtf(s) : 0.f;
        }
        __syncthreads();

        // t_s: per-wave row reductions
        {
            const int j = t & 63, q = t >> 6;
            const float dj = dinv_s[j];
            for (int i = q * 16; i < q * 16 + 16; i++) {
                float vv = ew_s[i * NPG + j] * dj;
                #pragma unroll
                for (int off = 32; off > 0; off >>= 1) vv += __shfl_down(vv, off, 64);
                if (j == 0) t_s[i] = dinv_s[i] * vv * (1.f / 64.f);
            }
        }

        // P = x @ W1h : thread (f = t&63, ih = t>>6) does 16 rows
        {
            const int f = t & 63, ih = t >> 6;
            for (int i = ih * 16; i < ih * 16 + 16; i++) {
                float acc = 0.f;
                #pragma unroll
                for (int k = 0; k < IN; k++) acc += x_s[i * IN + k] * W1h_s[k * 64 + f];
                P_s[i * 64 + f] = acc;
            }
        }
        __syncthreads();

        // scale rows in place: ew_s[i][j] = dinv_i * ew[i][j]
        for (int i = t; i < EPG; i += 256) ew_s[i] *= dinv_s[i >> 6];
        __syncthreads();

        // aggregation + relu + z-half: thread (j = t&63, q = t>>6) owns 16 f's
        {
            const int j = t & 63, q = t >> 6, fb = q * 16;
            float acc[16];
            #pragma unroll
            for (int uu = 0; uu < 16; uu++) acc[uu] = 0.f;
            for (int i = 0; i < NPG; i++) {
                const float w = ew_s[i * NPG + j];                     // 2-way (free)
                const float4* p4 = (const float4*)(P_s + i * 64 + fb); // wave-uniform
                #pragma unroll
                for (int u4 = 0; u4 < 4; u4++) {
                    float4 p = p4[u4];
                    acc[4 * u4 + 0] += w * p.x;
                    acc[4 * u4 + 1] += w * p.y;
                    acc[4 * u4 + 2] += w * p.z;
                    acc[4 * u4 + 3] += w * p.w;
                }
            }
            const float dj = dinv_s[j], tj = t_s[j];
            #pragma unroll
            for (int uu = 0; uu < 16; uu++) {
                float h = fmaxf(dj * acc[uu] + b1h_s[fb + uu], 0.f);
                float zv = tj * h;
                #pragma unroll
                for (int off = 32; off > 0; off >>= 1) zv += __shfl_down(zv, off, 64);
                if (j == 0) z[g * DM + fh0 + fb + uu] = zv;
            }
        }
    } else {
        // ---------------- gemm x/ew chunk path ----------------
        // chunk c: kc = c>>1 (64 feat cols), fh = c&1 (64 Wm0 cols)
        const int c = b - 256;
        const int kc = c >> 1, fh = c & 1;
        float* a_s = u;             // [k][g] 64*132 = 8448
        float* b_s = u + 8448;      // [k][fl] 64*64 = 4096

        const float* src; int stride, off;
        if (kc < 16) { src = x;  stride = 1024; off = kc * 64; }
        else         { src = ew; stride = 4096; off = (kc - 16) * 64; }
        const int K0 = 128 + kc * 64;   // global feat-col base = Wm0 row base

        #pragma unroll 4
        for (int it = 0; it < 32; it++) {
            int idx = it * 256 + t;
            int gg = idx >> 6, k = idx & 63;
            a_s[k * 132 + gg] = fmaxf(src[gg * stride + off + k], 0.f);  // feat relu
        }
        #pragma unroll 4
        for (int it = 0; it < 16; it++) {
            int idx = it * 256 + t;
            int k = idx >> 6, fl = idx & 63;
            b_s[k * 64 + fl] = Wm0[(K0 + k) * 128 + fh * 64 + fl];
        }
        __syncthreads();

        const int gthr = t & 31, fthr = t >> 5;   // 32 x 8
        const int g0 = gthr * 4, f0 = fthr * 8;
        float acc[4][8];
        #pragma unroll
        for (int i = 0; i < 4; i++)
            #pragma unroll
            for (int jx = 0; jx < 8; jx++) acc[i][jx] = 0.f;

        #pragma unroll 4
        for (int k = 0; k < 64; k++) {
            const float4 a4  = *(const float4*)(a_s + k * 132 + g0);
            const float4 c0v = *(const float4*)(b_s + k * 64 + f0);
            const float4 c1v = *(const float4*)(b_s + k * 64 + f0 + 4);
            const float av[4] = {a4.x, a4.y, a4.z, a4.w};
            const float bv[8] = {c0v.x, c0v.y, c0v.z, c0v.w, c1v.x, c1v.y, c1v.z, c1v.w};
            #pragma unroll
            for (int i = 0; i < 4; i++)
                #pragma unroll
                for (int jx = 0; jx < 8; jx++) acc[i][jx] += av[i] * bv[jx];
        }

        float* pp = part + c * 8192;    // [g][fl] 128x64
        #pragma unroll
        for (int i = 0; i < 4; i++) {
            float4* o = (float4*)(pp + (g0 + i) * 64 + f0);
            o[0] = make_float4(acc[i][0], acc[i][1], acc[i][2], acc[i][3]);
            o[1] = make_float4(acc[i][4], acc[i][5], acc[i][6], acc[i][7]);
        }
    }
}

// ---------------------------------------------------------------------------
// K_P: pooled = relu(z@W2 + b2)  [128x128], then pooled_part = pooled @ Wm0[0:128,:]
// 64 blocks x 2 graph-rows. W2 and Wm0[0:128] staged whole (128KB LDS, 1 blk/CU).
// ---------------------------------------------------------------------------
__global__ __launch_bounds__(256) void k_pooled(
    const float* __restrict__ zbuf, const float* __restrict__ W2,
    const float* __restrict__ b2, const float* __restrict__ Wm0,
    float* __restrict__ pooled_part)
{
    __shared__ float W2_s[16384];      // 64KB
    __shared__ float Wm0_s[16384];     // 64KB (rows 0..127 = pooled rows)
    __shared__ float z_s[256];
    __shared__ float pooled_s[2 * 130];
    const int bb = blockIdx.x, t = threadIdx.x, g0 = bb * 2;

    for (int i = t; i < 4096; i += 256) {
        ((float4*)W2_s)[i]  = ((const float4*)W2)[i];
        ((float4*)Wm0_s)[i] = ((const float4*)Wm0)[i];
    }
    if (t < 64) ((float4*)z_s)[t] = ((const float4*)(zbuf + g0 * DM))[t];
    __syncthreads();

    const int cc = t & 127, r = t >> 7;
    float acc = b2[cc];
    #pragma unroll 8
    for (int k = 0; k < DM; k++) acc += z_s[r * DM + k] * W2_s[k * DM + cc];
    pooled_s[r * 130 + cc] = fmaxf(acc, 0.f);
    __syncthreads();

    float acc2 = 0.f;
    #pragma unroll 8
    for (int k = 0; k < DM; k++) acc2 += pooled_s[r * 130 + k] * Wm0_s[k * DM + cc];
    pooled_part[(g0 + r) * DM + cc] = acc2;
}

// ---------------------------------------------------------------------------
// K_B: reduce 160 partials (+ pooled_part) + bm0 + relu -> v0; BN0 stats atomics.
// 256 blocks = 32 g-tiles x 8 f-grps; threads = 16 f x 4 g x 4 k-chunk-quarters.
// ---------------------------------------------------------------------------
__global__ __launch_bounds__(256) void k_reduce_bn0(
    const float* __restrict__ part, const float* __restrict__ pooled_part,
    const float* __restrict__ bm0, float* __restrict__ v0,
    float* __restrict__ stats0)
{
    const int bx = blockIdx.x, t = threadIdx.x;
    const int fgrp = bx & 7, gt = bx >> 3;
    const int fsub = t & 15, gl = (t >> 4) & 3, ch = t >> 6;
    const int f = fgrp * 16 + fsub, g = gt * 4 + gl;
    const int fh = f >> 6, fl = f & 63;

    const float* p = part + (size_t)(2 * (ch * 20) + fh) * 8192 + g * 64 + fl;
    float v = 0.f;
    #pragma unroll 5
    for (int cc = 0; cc < 20; cc++) v += p[(size_t)cc * 2 * 8192];

    __shared__ float r1[256];
    r1[t] = v;
    __syncthreads();
    __shared__ float sv[64], sv2[64];
    if (ch == 0) {
        v = r1[t] + r1[t + 64] + r1[t + 128] + r1[t + 192]
          + bm0[f] + pooled_part[g * DM + f];
        v = fmaxf(v, 0.f);
        v0[g * DM + f] = v;
        sv[t] = v; sv2[t] = v * v;
    }
    __syncthreads();
    if (t < 16) {
        float s1 = sv[t] + sv[t + 16] + sv[t + 32] + sv[t + 48];
        float s2 = sv2[t] + sv2[t + 16] + sv2[t + 32] + sv2[t + 48];
        atomicAdd(&stats0[(fgrp * 16 + t) * 2], s1);
        atomicAdd(&stats0[(fgrp * 16 + t) * 2 + 1], s2);
    }
}

// ---------------------------------------------------------------------------
// K5/K6: one MLP layer. Block = output column f; 256 threads (split-K dot).
// BN of the PREVIOUS layer folded into the staging load.
// ---------------------------------------------------------------------------
__global__ __launch_bounds__(256) void k_mlp(
    const float* __restrict__ vin, const float* __restrict__ statsin,
    const float* __restrict__ gbn, const float* __restrict__ bbn,
    const float* __restrict__ W, const float* __restrict__ bias,
    float* __restrict__ vout, float* __restrict__ statsout)
{
    __shared__ float h_s[128 * 129];
    __shared__ float wcol[128];
    __shared__ float scale_s[128], shift_s[128];
    __shared__ float pc[128];
    __shared__ float rr[4];
    const int f = blockIdx.x, t = threadIdx.x;
    if (t < 128) {
        float s1 = statsin[t * 2], s2 = statsin[t * 2 + 1];
        float m = s1 * (1.f / 128.f);
        float var = s2 * (1.f / 128.f) - m * m;
        float sc = gbn[t] * rsqrtf(var + BN_EPS);
        scale_s[t] = sc;
        shift_s[t] = bbn[t] - m * sc;
        wcol[t] = W[t * 128 + f];
    }
    __syncthreads();
    #pragma unroll 4
    for (int it = 0; it < 64; it++) {
        int idx = it * 256 + t;
        int g = idx >> 7, k = idx & 127;
        h_s[g * 129 + k] = vin[idx] * scale_s[k] + shift_s[k];
    }
    __syncthreads();
    const int g = t & 127, kh = t >> 7;
    float acc = 0.f;
    #pragma unroll 8
    for (int k = kh * 64; k < kh * 64 + 64; k++) acc += h_s[g * 129 + k] * wcol[k];
    if (kh) pc[g] = acc;
    __syncthreads();
    if (t < 128) {
        float v = fmaxf(acc + pc[t] + bias[f], 0.f);
        vout[t * 128 + f] = v;
        float s1 = v, s2 = v * v;
        #pragma unroll
        for (int off = 32; off > 0; off >>= 1) {
            s1 += __shfl_down(s1, off, 64);
            s2 += __shfl_down(s2, off, 64);
        }
        if ((t & 63) == 0) { rr[(t >> 6) * 2] = s1; rr[(t >> 6) * 2 + 1] = s2; }
    }
    __syncthreads();
    if (t == 0) {
        statsout[f * 2]     = rr[0] + rr[2];
        statsout[f * 2 + 1] = rr[1] + rr[3];
    }
}

// ---------------------------------------------------------------------------
// K7: output layer (BN2 folded at load). Block = 2 graph rows; coalesced out.
// ---------------------------------------------------------------------------
__global__ __launch_bounds__(128) void k_out(
    const float* __restrict__ vin, const float* __restrict__ statsin,
    const float* __restrict__ gbn, const float* __restrict__ bbn,
    const float* __restrict__ Wo, const float* __restrict__ bo,
    float* __restrict__ out)
{
    __shared__ float Wo_s[128 * 64];   // 32KB
    __shared__ float vrow[2][128];
    __shared__ float scale_s[128], shift_s[128];
    const int b = blockIdx.x, t = threadIdx.x, g0 = b * 2;
    {
        float s1 = statsin[t * 2], s2 = statsin[t * 2 + 1];
        float m = s1 * (1.f / 128.f);
        float var = s2 * (1.f / 128.f) - m * m;
        float sc = gbn[t] * rsqrtf(var + BN_EPS);
        scale_s[t] = sc;
        shift_s[t] = bbn[t] - m * sc;
    }
    __syncthreads();
    #pragma unroll 8
    for (int it = 0; it < 64; it++) {
        int idx = it * 128 + t;
        Wo_s[idx] = Wo[idx];
    }
    #pragma unroll
    for (int it = 0; it < 2; it++) {
        int idx = it * 128 + t;
        int g2 = idx >> 7, k = idx & 127;
        vrow[g2][k] = vin[(g0 + g2) * 128 + k] * scale_s[k] + shift_s[k];
    }
    __syncthreads();
    const int g2 = t >> 6, o = t & 63;
    float acc = bo[o];
    #pragma unroll 8
    for (int k = 0; k < 128; k++) acc += vrow[g2][k] * Wo_s[k * 64 + o];
    out[(g0 + g2) * NOUT + o] = acc;
}

extern "C" void kernel_launch(void* const* d_in, const int* in_sizes, int n_in,
                              void* d_out, int out_size, void* d_ws, size_t ws_size,
                              hipStream_t stream)
{
    const float* x   = (const float*)d_in[0];
    const float* ew  = (const float*)d_in[2];
    const float* W1  = (const float*)d_in[4];
    const float* b1  = (const float*)d_in[5];
    const float* W2  = (const float*)d_in[6];
    const float* b2  = (const float*)d_in[7];
    const float* Wm0 = (const float*)d_in[8];
    const float* bm0 = (const float*)d_in[9];
    const float* g0  = (const float*)d_in[10];
    const float* be0 = (const float*)d_in[11];
    const float* Wm1 = (const float*)d_in[12];
    const float* bm1 = (const float*)d_in[13];
    const float* g1  = (const float*)d_in[14];
    const float* be1 = (const float*)d_in[15];
    const float* Wm2 = (const float*)d_in[16];
    const float* bm2 = (const float*)d_in[17];
    const float* g2  = (const float*)d_in[18];
    const float* be2 = (const float*)d_in[19];
    const float* Wo  = (const float*)d_in[20];
    const float* bo  = (const float*)d_in[21];

    float* ws     = (float*)d_ws;
    float* zbuf   = ws;                       // 16384
    float* part   = zbuf + 16384;             // 160*8192 = 1310720
    float* ppart  = part + NGEMM * 8192;      // 16384
    float* v0     = ppart + 16384;            // 16384
    float* v1     = v0 + 16384;               // 16384
    float* v2     = v1 + 16384;               // 16384
    float* stats  = v2 + 16384;               // 768 (stats0|stats1|stats2)

    k_front<<<256 + NGEMM, 256, 0, stream>>>(x, ew, W1, b1, Wm0, zbuf, part, stats);
    k_pooled<<<64, 256, 0, stream>>>(zbuf, W2, b2, Wm0, ppart);
    k_reduce_bn0<<<256, 256, 0, stream>>>(part, ppart, bm0, v0, stats);
    k_mlp<<<128, 256, 0, stream>>>(v0, stats,       g0, be0, Wm1, bm1, v1, stats + 256);
    k_mlp<<<128, 256, 0, stream>>>(v1, stats + 256, g1, be1, Wm2, bm2, v2, stats + 512);
    k_out<<<NOUT, 128, 0, stream>>>(v2, stats + 512, g2, be2, Wo, bo, (float*)d_out);
}

// Round 4
// 140.413 us; speedup vs baseline: 1.2518x; 1.0557x over previous
//
#include <hip/hip_runtime.h>

#define NG 128      // graphs
#define NPG 64      // nodes per graph
#define IN 16
#define DM 128      // d_model
#define NOUT 64
#define EPG 4096    // edges per graph (64x64)
#define NGEMM 160   // x/ew chunks: 80 k-chunks(64) x 2 f-halves(64)
#define BN_EPS 1e-5f

// ---------------------------------------------------------------------------
// K_A "front": blocks 0..255 = conv1 per (graph, f-half) -> z;
//              blocks 256..415 = big-GEMM x/ew chunks (64k x 64f) -> part.
// Block 0 also zeroes the 768-float stats region.
// ---------------------------------------------------------------------------
__global__ __launch_bounds__(256) void k_front(
    const float* __restrict__ x, const float* __restrict__ ew,
    const float* __restrict__ W1, const float* __restrict__ b1,
    const float* __restrict__ Wm0,
    float* __restrict__ z, float* __restrict__ part, float* __restrict__ stats)
{
    __shared__ __align__(16) float u[12544];   // 49KB union
    const int b = blockIdx.x, t = threadIdx.x;

    if (b < 256) {
        // ---------------- conv path ----------------
        float* ew_s   = u;            // 4096  [i][j], later scaled by dinv_i
        float* x_s    = u + 4096;     // 1024
        float* W1h_s  = u + 5120;     // 1024
        float* P_s    = u + 6144;     // 4096
        float* b1h_s  = u + 10240;    // 64
        float* dinv_s = u + 10304;    // 64
        float* t_s    = u + 10368;    // 64
        const int g = b >> 1, half = b & 1, fh0 = half * 64;
        if (b == 0) {
            for (int i = t; i < 768; i += 256) stats[i] = 0.f;
        }
        {
            const float4* ew4 = (const float4*)(ew + g * EPG);
            float4* ews4 = (float4*)ew_s;
            #pragma unroll
            for (int i = 0; i < 4; i++) ews4[t + 256 * i] = ew4[t + 256 * i];
            ((float4*)x_s)[t] = ((const float4*)(x + g * NPG * IN))[t];
        }
        for (int i = t; i < IN * 64; i += 256)
            W1h_s[i] = W1[(i >> 6) * DM + fh0 + (i & 63)];
        if (t < 64) b1h_s[t] = b1[fh0 + t];
        __syncthreads();

        if (t < NPG) {
            float s = 0.f;
            #pragma unroll 8
            for (int i = 0; i < NPG; i++) s += ew_s[i * NPG + t];
            dinv_s[t] = (s > 0.f) ? rsqrtf(s) : 0.f;
        }
        __syncthreads();

        {
            const int j = t & 63, q = t >> 6;
            const float dj = dinv_s[j];
            for (int i = q * 16; i < q * 16 + 16; i++) {
                float vv = ew_s[i * NPG + j] * dj;
                #pragma unroll
                for (int off = 32; off > 0; off >>= 1) vv += __shfl_down(vv, off, 64);
                if (j == 0) t_s[i] = dinv_s[i] * vv * (1.f / 64.f);
            }
        }

        {
            const int f = t & 63, ih = t >> 6;
            for (int i = ih * 16; i < ih * 16 + 16; i++) {
                float acc = 0.f;
                #pragma unroll
                for (int k = 0; k < IN; k++) acc += x_s[i * IN + k] * W1h_s[k * 64 + f];
                P_s[i * 64 + f] = acc;
            }
        }
        __syncthreads();

        for (int i = t; i < EPG; i += 256) ew_s[i] *= dinv_s[i >> 6];
        __syncthreads();

        {
            const int j = t & 63, q = t >> 6, fb = q * 16;
            float acc[16];
            #pragma unroll
            for (int uu = 0; uu < 16; uu++) acc[uu] = 0.f;
            for (int i = 0; i < NPG; i++) {
                const float w = ew_s[i * NPG + j];
                const float4* p4 = (const float4*)(P_s + i * 64 + fb);
                #pragma unroll
                for (int u4 = 0; u4 < 4; u4++) {
                    float4 p = p4[u4];
                    acc[4 * u4 + 0] += w * p.x;
                    acc[4 * u4 + 1] += w * p.y;
                    acc[4 * u4 + 2] += w * p.z;
                    acc[4 * u4 + 3] += w * p.w;
                }
            }
            const float dj = dinv_s[j], tj = t_s[j];
            #pragma unroll
            for (int uu = 0; uu < 16; uu++) {
                float h = fmaxf(dj * acc[uu] + b1h_s[fb + uu], 0.f);
                float zv = tj * h;
                #pragma unroll
                for (int off = 32; off > 0; off >>= 1) zv += __shfl_down(zv, off, 64);
                if (j == 0) z[g * DM + fh0 + fb + uu] = zv;
            }
        }
    } else {
        // ---------------- gemm x/ew chunk path ----------------
        const int c = b - 256;
        const int kc = c >> 1, fh = c & 1;
        float* a_s = u;             // [k][g] 64*132 = 8448
        float* b_s = u + 8448;      // [k][fl] 64*64 = 4096

        const float* src; int stride, off;
        if (kc < 16) { src = x;  stride = 1024; off = kc * 64; }
        else         { src = ew; stride = 4096; off = (kc - 16) * 64; }
        const int K0 = 128 + kc * 64;

        #pragma unroll 4
        for (int it = 0; it < 32; it++) {
            int idx = it * 256 + t;
            int gg = idx >> 6, k = idx & 63;
            a_s[k * 132 + gg] = fmaxf(src[gg * stride + off + k], 0.f);
        }
        #pragma unroll 4
        for (int it = 0; it < 16; it++) {
            int idx = it * 256 + t;
            int k = idx >> 6, fl = idx & 63;
            b_s[k * 64 + fl] = Wm0[(K0 + k) * 128 + fh * 64 + fl];
        }
        __syncthreads();

        const int gthr = t & 31, fthr = t >> 5;   // 32 x 8
        const int g0 = gthr * 4, f0 = fthr * 8;
        float acc[4][8];
        #pragma unroll
        for (int i = 0; i < 4; i++)
            #pragma unroll
            for (int jx = 0; jx < 8; jx++) acc[i][jx] = 0.f;

        #pragma unroll 4
        for (int k = 0; k < 64; k++) {
            const float4 a4  = *(const float4*)(a_s + k * 132 + g0);
            const float4 c0v = *(const float4*)(b_s + k * 64 + f0);
            const float4 c1v = *(const float4*)(b_s + k * 64 + f0 + 4);
            const float av[4] = {a4.x, a4.y, a4.z, a4.w};
            const float bv[8] = {c0v.x, c0v.y, c0v.z, c0v.w, c1v.x, c1v.y, c1v.z, c1v.w};
            #pragma unroll
            for (int i = 0; i < 4; i++)
                #pragma unroll
                for (int jx = 0; jx < 8; jx++) acc[i][jx] += av[i] * bv[jx];
        }

        float* pp = part + c * 8192;    // [g][fl] 128x64
        #pragma unroll
        for (int i = 0; i < 4; i++) {
            float4* o = (float4*)(pp + (g0 + i) * 64 + f0);
            o[0] = make_float4(acc[i][0], acc[i][1], acc[i][2], acc[i][3]);
            o[1] = make_float4(acc[i][4], acc[i][5], acc[i][6], acc[i][7]);
        }
    }
}

// ---------------------------------------------------------------------------
// K_B: reduce 160 partials + (in-block) pooled contribution + bm0 + relu -> v0;
// BN0 stats atomics. 256 blocks = 32 g-tiles x 8 f-grps.
// pooled = relu(z@W2+b2) recomputed per block for its 4 graphs (cheap),
// pooled_part slice = pooled @ Wm0[0:128, f-slice].
// ---------------------------------------------------------------------------
__global__ __launch_bounds__(256) void k_reduce_bn0(
    const float* __restrict__ part, const float* __restrict__ zbuf,
    const float* __restrict__ W2, const float* __restrict__ b2,
    const float* __restrict__ Wm0, const float* __restrict__ bm0,
    float* __restrict__ v0, float* __restrict__ stats0)
{
    __shared__ __align__(16) float W2_s[16384];     // 64KB [m][k]
    __shared__ __align__(16) float z_s[512];        // 4 graph rows
    __shared__ float Wm0s[2048];                    // [k][fsub] 8KB
    __shared__ float pooled_s[4 * 130];
    __shared__ float pps[64];
    __shared__ float r1[256];
    __shared__ float sv[64], sv2[64];

    const int bx = blockIdx.x, t = threadIdx.x;
    const int fgrp = bx & 7, gt = bx >> 3;
    const int fsub = t & 15, gl = (t >> 4) & 3, ch = t >> 6;
    const int f = fgrp * 16 + fsub, g = gt * 4 + gl;
    const int fh = f >> 6, fl = f & 63;

    // partial-sum over this thread's 20 k-chunks (global, L2/L3)
    const float* p = part + (size_t)(2 * (ch * 20) + fh) * 8192 + g * 64 + fl;
    float v = 0.f;
    #pragma unroll 5
    for (int cc = 0; cc < 20; cc++) v += p[(size_t)cc * 2 * 8192];

    // stage W2 (full), z rows, Wm0 f-slice
    {
        const float4* w24 = (const float4*)W2;
        float4* w2s4 = (float4*)W2_s;
        #pragma unroll
        for (int i = 0; i < 16; i++) w2s4[t + 256 * i] = w24[t + 256 * i];
        if (t < 128) ((float4*)z_s)[t] = ((const float4*)(zbuf + gt * 512))[t];
        for (int idx = t; idx < 2048; idx += 256) {
            int k = idx >> 4, fs = idx & 15;
            Wm0s[idx] = Wm0[k * DM + fgrp * 16 + fs];
        }
    }
    r1[t] = v;
    __syncthreads();

    // pooled rows for this block's 4 graphs: thread (gp = t>>6, k0 = t&63) does k0, k0+64
    {
        const int gp = t >> 6, k0 = t & 63;
        float a0 = 0.f, a1 = 0.f;
        #pragma unroll 4
        for (int m = 0; m < DM; m++) {
            const float zm = z_s[gp * DM + m];
            a0 += zm * W2_s[m * DM + k0];
            a1 += zm * W2_s[m * DM + k0 + 64];
        }
        pooled_s[gp * 130 + k0]      = fmaxf(a0 + b2[k0], 0.f);
        pooled_s[gp * 130 + k0 + 64] = fmaxf(a1 + b2[k0 + 64], 0.f);
    }
    __syncthreads();

    // pooled_part slice: t<64 -> (gl2 = t>>4, fs = t&15)
    if (t < 64) {
        const int gl2 = t >> 4, fs = t & 15;
        float a = 0.f;
        #pragma unroll 8
        for (int k = 0; k < DM; k++) a += pooled_s[gl2 * 130 + k] * Wm0s[k * 16 + fs];
        pps[t] = a;
    }
    __syncthreads();

    if (ch == 0) {
        v = r1[t] + r1[t + 64] + r1[t + 128] + r1[t + 192]
          + bm0[f] + pps[t];
        v = fmaxf(v, 0.f);
        v0[g * DM + f] = v;
        sv[t] = v; sv2[t] = v * v;
    }
    __syncthreads();
    if (t < 16) {
        float s1 = sv[t] + sv[t + 16] + sv[t + 32] + sv[t + 48];
        float s2 = sv2[t] + sv2[t + 16] + sv2[t + 32] + sv2[t + 48];
        atomicAdd(&stats0[(fgrp * 16 + t) * 2], s1);
        atomicAdd(&stats0[(fgrp * 16 + t) * 2 + 1], s2);
    }
}

// ---------------------------------------------------------------------------
// K5/K6: one MLP layer. Block = output column f; 256 threads (split-K dot).
// BN of the PREVIOUS layer folded into the (float4) staging load.
// ---------------------------------------------------------------------------
__global__ __launch_bounds__(256) void k_mlp(
    const float* __restrict__ vin, const float* __restrict__ statsin,
    const float* __restrict__ gbn, const float* __restrict__ bbn,
    const float* __restrict__ W, const float* __restrict__ bias,
    float* __restrict__ vout, float* __restrict__ statsout)
{
    __shared__ float h_s[128 * 129];
    __shared__ float wcol[128];
    __shared__ float scale_s[128], shift_s[128];
    __shared__ float pc[128];
    __shared__ float rr[4];
    const int f = blockIdx.x, t = threadIdx.x;
    if (t < 128) {
        float s1 = statsin[t * 2], s2 = statsin[t * 2 + 1];
        float m = s1 * (1.f / 128.f);
        float var = s2 * (1.f / 128.f) - m * m;
        float sc = gbn[t] * rsqrtf(var + BN_EPS);
        scale_s[t] = sc;
        shift_s[t] = bbn[t] - m * sc;
        wcol[t] = W[t * 128 + f];
    }
    __syncthreads();
    #pragma unroll 4
    for (int it = 0; it < 16; it++) {
        int idx = it * 256 + t;           // float4 index (4096 total)
        int g = idx >> 5, k4 = (idx & 31) * 4;
        float4 vv = ((const float4*)vin)[idx];
        float* hp = h_s + g * 129 + k4;
        hp[0] = vv.x * scale_s[k4 + 0] + shift_s[k4 + 0];
        hp[1] = vv.y * scale_s[k4 + 1] + shift_s[k4 + 1];
        hp[2] = vv.z * scale_s[k4 + 2] + shift_s[k4 + 2];
        hp[3] = vv.w * scale_s[k4 + 3] + shift_s[k4 + 3];
    }
    __syncthreads();
    const int g = t & 127, kh = t >> 7;
    float acc = 0.f;
    #pragma unroll 8
    for (int k = kh * 64; k < kh * 64 + 64; k++) acc += h_s[g * 129 + k] * wcol[k];
    if (kh) pc[g] = acc;
    __syncthreads();
    if (t < 128) {
        float v = fmaxf(acc + pc[t] + bias[f], 0.f);
        vout[t * 128 + f] = v;
        float s1 = v, s2 = v * v;
        #pragma unroll
        for (int off = 32; off > 0; off >>= 1) {
            s1 += __shfl_down(s1, off, 64);
            s2 += __shfl_down(s2, off, 64);
        }
        if ((t & 63) == 0) { rr[(t >> 6) * 2] = s1; rr[(t >> 6) * 2 + 1] = s2; }
    }
    __syncthreads();
    if (t == 0) {
        statsout[f * 2]     = rr[0] + rr[2];
        statsout[f * 2 + 1] = rr[1] + rr[3];
    }
}

// ---------------------------------------------------------------------------
// K7: output layer (BN2 folded at load). Block = 2 graph rows; coalesced out.
// ---------------------------------------------------------------------------
__global__ __launch_bounds__(128) void k_out(
    const float* __restrict__ vin, const float* __restrict__ statsin,
    const float* __restrict__ gbn, const float* __restrict__ bbn,
    const float* __restrict__ Wo, const float* __restrict__ bo,
    float* __restrict__ out)
{
    __shared__ __align__(16) float Wo_s[128 * 64];   // 32KB
    __shared__ float vrow[2][128];
    __shared__ float scale_s[128], shift_s[128];
    const int b = blockIdx.x, t = threadIdx.x, g0 = b * 2;
    {
        float s1 = statsin[t * 2], s2 = statsin[t * 2 + 1];
        float m = s1 * (1.f / 128.f);
        float var = s2 * (1.f / 128.f) - m * m;
        float sc = gbn[t] * rsqrtf(var + BN_EPS);
        scale_s[t] = sc;
        shift_s[t] = bbn[t] - m * sc;
    }
    __syncthreads();
    {
        const float4* wo4 = (const float4*)Wo;
        float4* wos4 = (float4*)Wo_s;
        #pragma unroll
        for (int it = 0; it < 16; it++) wos4[it * 128 + t] = wo4[it * 128 + t];
    }
    if (t < 64) {
        int g2 = t >> 5, k4 = (t & 31) * 4;
        float4 vv = ((const float4*)(vin + g0 * 128))[t];
        vrow[g2][k4 + 0] = vv.x * scale_s[k4 + 0] + shift_s[k4 + 0];
        vrow[g2][k4 + 1] = vv.y * scale_s[k4 + 1] + shift_s[k4 + 1];
        vrow[g2][k4 + 2] = vv.z * scale_s[k4 + 2] + shift_s[k4 + 2];
        vrow[g2][k4 + 3] = vv.w * scale_s[k4 + 3] + shift_s[k4 + 3];
    }
    __syncthreads();
    const int g2 = t >> 6, o = t & 63;
    float acc = bo[o];
    #pragma unroll 8
    for (int k = 0; k < 128; k++) acc += vrow[g2][k] * Wo_s[k * 64 + o];
    out[(g0 + g2) * NOUT + o] = acc;
}

extern "C" void kernel_launch(void* const* d_in, const int* in_sizes, int n_in,
                              void* d_out, int out_size, void* d_ws, size_t ws_size,
                              hipStream_t stream)
{
    const float* x   = (const float*)d_in[0];
    const float* ew  = (const float*)d_in[2];
    const float* W1  = (const float*)d_in[4];
    const float* b1  = (const float*)d_in[5];
    const float* W2  = (const float*)d_in[6];
    const float* b2  = (const float*)d_in[7];
    const float* Wm0 = (const float*)d_in[8];
    const float* bm0 = (const float*)d_in[9];
    const float* g0  = (const float*)d_in[10];
    const float* be0 = (const float*)d_in[11];
    const float* Wm1 = (const float*)d_in[12];
    const float* bm1 = (const float*)d_in[13];
    const float* g1  = (const float*)d_in[14];
    const float* be1 = (const float*)d_in[15];
    const float* Wm2 = (const float*)d_in[16];
    const float* bm2 = (const float*)d_in[17];
    const float* g2  = (const float*)d_in[18];
    const float* be2 = (const float*)d_in[19];
    const float* Wo  = (const float*)d_in[20];
    const float* bo  = (const float*)d_in[21];

    float* ws     = (float*)d_ws;
    float* zbuf   = ws;                       // 16384
    float* part   = zbuf + 16384;             // 160*8192 = 1310720
    float* v0     = part + NGEMM * 8192;      // 16384
    float* v1     = v0 + 16384;               // 16384
    float* v2     = v1 + 16384;               // 16384
    float* stats  = v2 + 16384;               // 768 (stats0|stats1|stats2)

    k_front<<<256 + NGEMM, 256, 0, stream>>>(x, ew, W1, b1, Wm0, zbuf, part, stats);
    k_reduce_bn0<<<256, 256, 0, stream>>>(part, zbuf, W2, b2, Wm0, bm0, v0, stats);
    k_mlp<<<128, 256, 0, stream>>>(v0, stats,       g0, be0, Wm1, bm1, v1, stats + 256);
    k_mlp<<<128, 256, 0, stream>>>(v1, stats + 256, g1, be1, Wm2, bm2, v2, stats + 512);
    k_out<<<NOUT, 128, 0, stream>>>(v2, stats + 512, g2, be2, Wo, bo, (float*)d_out);
}